// Round 11
// baseline (120.648 us; speedup 1.0000x reference)
//
#include <hip/hip_runtime.h>

// DropGCN: out = relu( mean_r( diag(k_r) A diag(k_r) X ) @ W^T + b )
//  == Y[8192,160] = A @ Xm   (Xm[:, r*32+d] = k_r .* X[:,d], bf16)
//  then per-row masked mean over the 5 replica slices, @W^T, +b, relu.
//
// Round 11: r10 with the prep mask-LDS init bug fixed (mf[320] was written
// by only 256 threads under `if (tid < 320)` -> replica 4 read garbage;
// now a strided loop covers all 320). Rest byte-identical to r10: A staged
// through LDS with FULLY-COALESCED loads (1 KB/instruction), BK=64, XOR-
// swizzled A tile + pre-swizzled Xm slices, 8 waves x 16-row m-tiles,
// KSPLIT=8, grid (64,8), 72 KB LDS, r8 dbuf/1-barrier skeleton.

#define N_NODES   8192
#define NCOLS     160          // 5 replicas * 32 dims
#define BK        64
#define NSLICE64  128          // 8192/64 K-slices
#define SLICE_US  10240        // ushorts per 64-k slice (160*64)
#define ATILE_US  8192         // ushorts per A tile (128 rows * 64 k)
#define MASK_WS   65536
#define KSPLIT    8
#define STEPS     16           // 1024 / BK

typedef __attribute__((ext_vector_type(4))) float f32x4;
typedef __attribute__((ext_vector_type(2))) unsigned int uint2v;
typedef __attribute__((ext_vector_type(8))) short bf16x8;

__device__ __forceinline__ unsigned short f2bf(float f) {
  unsigned int u = __builtin_bit_cast(unsigned int, f);
  return (unsigned short)((u + 0x7FFFu + ((u >> 16) & 1u)) >> 16);
}

__device__ __forceinline__ unsigned pack_bf(float lo, float hi) {
  unsigned u0 = __builtin_bit_cast(unsigned, lo) + 0x8000u;
  unsigned u1 = __builtin_bit_cast(unsigned, hi) + 0x8000u;
  return (u1 & 0xFFFF0000u) | (u0 >> 16);
}

// ---------------------------------------------------------------------------
// prep: block s64 handles K-slice [s64*64, +64) x all 160 cols. Coalesced X
// read -> LDS transpose; mask normalize; XmG written PRE-SWIZZLED in 16 B
// chunks: position (n, kcpos) holds data kc = kcpos ^ (n&7). Gemm stages
// linearly; fragment read applies the same involution (rule #21).
// ---------------------------------------------------------------------------
__global__ __launch_bounds__(256) void prep_kernel(
    const float* __restrict__ X, const void* __restrict__ raw,
    unsigned char* __restrict__ mk, unsigned short* __restrict__ XmG) {
  __shared__ float xt[64 * 33];   // [kk][d], pad 33
  __shared__ float mf[320];       // [r][kk] 0/1
  __shared__ int mode32s;
  const int tid = threadIdx.x;
  const int s = blockIdx.x;       // 0..127

  if (tid == 0) {
    const unsigned* wrd = (const unsigned*)raw;
    int ok = 1;
    for (int i = 0; i < 64; ++i) {
      unsigned v = wrd[i];
      if (!(v <= 1u || v == 0x3F800000u)) { ok = 0; break; }
    }
    mode32s = ok;
  }
  f32x4 xv0 = *(const f32x4*)(X + (size_t)s * 2048 + tid * 4);
  f32x4 xv1 = *(const f32x4*)(X + (size_t)s * 2048 + 1024 + tid * 4);
  __syncthreads();
  const int mode32 = mode32s;
#pragma unroll
  for (int q = 0; q < 4; ++q) {
    int e = tid * 4 + q;                 // e = kk*32 + d, kk 0..31
    xt[(e >> 5) * 33 + (e & 31)] = xv0[q];
    int e2 = 1024 + tid * 4 + q;         // kk 32..63
    xt[(e2 >> 5) * 33 + (e2 & 31)] = xv1[q];
  }
  // FIX (r10 bug): cover all 320 entries with 256 threads
  for (int t = tid; t < 320; t += 256) {
    int r = t >> 6, jj = t & 63;
    int gi = r * N_NODES + s * 64 + jj;
    unsigned char kv = mode32 ? (unsigned char)(((const unsigned*)raw)[gi] != 0u)
                              : (unsigned char)(((const unsigned char*)raw)[gi] != 0);
    mk[gi] = kv;
    mf[t] = kv ? 1.0f : 0.0f;
  }
  __syncthreads();

  unsigned short* outp = XmG + (size_t)s * SLICE_US;
#pragma unroll
  for (int i = 0; i < 5; ++i) {
    int c = tid + i * 256;               // chunk 0..1279
    int n = c >> 3;
    int kc = (c & 7) ^ (n & 7);          // pre-swizzle (involution)
    int r = n >> 5, d = n & 31;
    union { bf16x8 v; unsigned short us[8]; } o;
#pragma unroll
    for (int e = 0; e < 8; ++e) {
      int kk = kc * 8 + e;
      o.us[e] = f2bf(mf[r * 64 + kk] * xt[kk * 33 + d]);
    }
    *(bf16x8*)(outp + c * 8) = o.v;
  }
}

// ---------------------------------------------------------------------------
// gemm: block = 8 waves, 128 rows, all 160 cols, K-range 1024 (16 steps of
// BK=64). Per step: stage A tile 128x64 f32 -> bf16 LDS (COALESCED: thread
// reads one f32x4 from each of 4 rows, 16 lanes = 256 B contiguous/row),
// stage Xm slice (linear, pre-swizzled). Wave w owns rows [w*16,+16).
// A-LDS swizzle: 8 B slot s4 (=kk/4) stored at s4 ^ ((row&7)<<1); 8-ushort
// frag reads span slot pair {p, p+1} with p even (kg*2 and xsw both even),
// so reads stay in-row and the involution resolves per-slot.
// Xm-LDS: chunk (n, kc) at position kc ^ (n&7).
// Verified D map: acc[nt][jj] = Y[m][nt*16 + kg*4 + jj].
// Fused replica mask-mean epilogue -> partZ[sy][m][d] f32.
// ---------------------------------------------------------------------------
__global__ __launch_bounds__(512, 2) void gemm_kernel(
    const float* __restrict__ A, const unsigned short* __restrict__ XmG,
    const unsigned char* __restrict__ mk, float* __restrict__ partZ) {
  __shared__ __align__(16) unsigned short Ax[2][ATILE_US];   // 32 KB
  __shared__ __align__(16) unsigned short Xs[2][SLICE_US];   // 40 KB

  const int tid  = threadIdx.x;
  const int lane = tid & 63;
  const int w    = tid >> 6;        // wave 0..7
  const int n0   = lane & 15;
  const int kg   = lane >> 4;       // k-group 0..3
  const int sy   = blockIdx.y;      // k-split 0..7
  const int bx   = blockIdx.x;      // m-block 0..63

  // ---- A staging geometry: thread covers rows j*32+srow, 16 B each ----
  const int srow   = tid >> 4;      // 0..31
  const int scol16 = tid & 15;      // 16 B column within the 256 B row-chunk
  const float* aG = A + (size_t)(bx * 128 + srow) * N_NODES +
                    (size_t)sy * 1024 + scol16 * 4;
  const int s4sw = scol16 ^ ((srow & 7) << 1);   // same for all j (32%8==0)

  // ---- Xm staging: 1280 chunks over 512 threads (linear) ----
  const unsigned short* xmbase = XmG + (size_t)sy * STEPS * SLICE_US;
  const bool has3 = (tid < 256);

  // ---- fragment read bases ----
  const int rowf = w * 16 + n0;     // block-local A row
  const int xsw  = (rowf & 7) << 1;
  const int af0 = rowf * 64 + ((kg * 2) ^ xsw) * 4;        // ks=0
  const int af1 = rowf * 64 + ((8 + kg * 2) ^ xsw) * 4;    // ks=1
  const int xb0 = n0 * 64 + ((kg ^ (n0 & 7)) << 3);        // ks=0
  const int xb1 = n0 * 64 + (((4 + kg) ^ (n0 & 7)) << 3);  // ks=1

  f32x4 acc[10];
#pragma unroll
  for (int i = 0; i < 10; ++i) acc[i] = (f32x4){0.f, 0.f, 0.f, 0.f};

  f32x4 av0, av1, av2, av3;
  bf16x8 sx0, sx1, sx2;

#define LOADA(st)                                                              \
  {                                                                            \
    const float* g_ = aG + (size_t)(st) * BK;                                  \
    av0 = __builtin_nontemporal_load((const f32x4*)g_);                        \
    av1 = __builtin_nontemporal_load((const f32x4*)(g_ + (size_t)32 * N_NODES));\
    av2 = __builtin_nontemporal_load((const f32x4*)(g_ + (size_t)64 * N_NODES));\
    av3 = __builtin_nontemporal_load((const f32x4*)(g_ + (size_t)96 * N_NODES));\
  }

#define LOADX(st)                                                              \
  {                                                                            \
    const unsigned short* xs_ = xmbase + (size_t)(st) * SLICE_US;              \
    sx0 = *(const bf16x8*)(xs_ + tid * 8);                                     \
    sx1 = *(const bf16x8*)(xs_ + (tid + 512) * 8);                             \
    if (has3) sx2 = *(const bf16x8*)(xs_ + (tid + 1024) * 8);                  \
  }

#define WRITEAX(buf)                                                           \
  {                                                                            \
    unsigned short* ab_ = &Ax[buf][0];                                         \
    uint2v p_;                                                                 \
    p_[0] = pack_bf(av0[0], av0[1]); p_[1] = pack_bf(av0[2], av0[3]);          \
    *(uint2v*)(ab_ + (srow)*64 + s4sw * 4) = p_;                               \
    p_[0] = pack_bf(av1[0], av1[1]); p_[1] = pack_bf(av1[2], av1[3]);          \
    *(uint2v*)(ab_ + (32 + srow) * 64 + s4sw * 4) = p_;                        \
    p_[0] = pack_bf(av2[0], av2[1]); p_[1] = pack_bf(av2[2], av2[3]);          \
    *(uint2v*)(ab_ + (64 + srow) * 64 + s4sw * 4) = p_;                        \
    p_[0] = pack_bf(av3[0], av3[1]); p_[1] = pack_bf(av3[2], av3[3]);          \
    *(uint2v*)(ab_ + (96 + srow) * 64 + s4sw * 4) = p_;                        \
    unsigned short* xb_ = &Xs[buf][0];                                         \
    *(bf16x8*)(xb_ + tid * 8) = sx0;                                           \
    *(bf16x8*)(xb_ + (tid + 512) * 8) = sx1;                                   \
    if (has3) *(bf16x8*)(xb_ + (tid + 1024) * 8) = sx2;                        \
  }

  // prologue: step0 -> LDS buf0; step1 -> regs
  LOADA(0); LOADX(0);
  WRITEAX(0);
  LOADA(1); LOADX(1);
  __syncthreads();

  int cur = 0;
  for (int step = 0; step < STEPS; ++step) {
    if (step + 1 < STEPS) { WRITEAX(cur ^ 1); }   // regs hold step+1
    if (step + 2 < STEPS) { LOADA(step + 2); LOADX(step + 2); }

#pragma unroll
    for (int ks = 0; ks < 2; ++ks) {
      bf16x8 bf = *(const bf16x8*)(&Ax[cur][ks ? af1 : af0]);
      const int xb = ks ? xb1 : xb0;
#pragma unroll
      for (int nt = 0; nt < 10; ++nt) {
        bf16x8 xf = *(const bf16x8*)(&Xs[cur][xb + nt * 1024]);
        acc[nt] = __builtin_amdgcn_mfma_f32_16x16x32_bf16(xf, bf, acc[nt], 0, 0, 0);
      }
    }
    __syncthreads();
    cur ^= 1;
  }

  // fused replica mask-mean epilogue (r8-verified map):
  // acc[2t][jj] = Y[m][32t + kg*4+jj], acc[2t+1][jj] = Y[m][32t+16+kg*4+jj]
  const int m = bx * 128 + w * 16 + n0;
  float wt[5];
#pragma unroll
  for (int t = 0; t < 5; ++t) wt[t] = mk[t * N_NODES + m] ? 0.2f : 0.0f;
  f32x4 zA = (f32x4){0.f, 0.f, 0.f, 0.f}, zB = zA;
#pragma unroll
  for (int t = 0; t < 5; ++t) {
    zA += wt[t] * acc[2 * t];
    zB += wt[t] * acc[2 * t + 1];
  }
  float* p = partZ + ((size_t)sy * N_NODES + m) * 32 + kg * 4;
  *(f32x4*)(p)      = zA;
  *(f32x4*)(p + 16) = zB;
}

// ---------------------------------------------------------------------------
// epi: z[m][d] = sum_s partZ[s][m][d];  out[m][o] = relu(b[o] + z . W[o])
// ---------------------------------------------------------------------------
__global__ __launch_bounds__(64) void epi_kernel(
    const float* __restrict__ partZ, const float* __restrict__ W,
    const float* __restrict__ bias, float* __restrict__ out) {
  __shared__ float sW[1024];
  __shared__ float sb[32];
  const int tid = threadIdx.x;
  for (int i = tid; i < 1024; i += 64) sW[i] = W[i];
  if (tid < 32) sb[tid] = bias[tid];
  __syncthreads();

  const int m = blockIdx.x * 64 + tid;
  float zz[32];
#pragma unroll
  for (int i = 0; i < 32; ++i) zz[i] = 0.f;
  const float* p = partZ + (size_t)m * 32;
  for (int s = 0; s < KSPLIT; ++s) {
    const float* ps = p + (size_t)s * N_NODES * 32;
#pragma unroll
    for (int i = 0; i < 8; ++i) {
      f32x4 v = *(const f32x4*)(ps + i * 4);
      zz[4 * i + 0] += v[0]; zz[4 * i + 1] += v[1];
      zz[4 * i + 2] += v[2]; zz[4 * i + 3] += v[3];
    }
  }
#pragma unroll
  for (int o = 0; o < 32; o += 4) {
    f32x4 r;
#pragma unroll
    for (int q = 0; q < 4; ++q) {
      float a = sb[o + q];
#pragma unroll
      for (int d = 0; d < 32; ++d) a = fmaf(zz[d], sW[(o + q) * 32 + d], a);
      r[q] = fmaxf(a, 0.f);
    }
    *(f32x4*)(out + (size_t)m * 32 + o) = r;
  }
}

extern "C" void kernel_launch(void* const* d_in, const int* in_sizes, int n_in,
                              void* d_out, int out_size, void* d_ws, size_t ws_size,
                              hipStream_t stream) {
  const float* A = (const float*)d_in[0];
  const float* X = (const float*)d_in[1];
  const float* W = (const float*)d_in[2];
  const float* b = (const float*)d_in[3];
  const void*  keep_raw = (const void*)d_in[4];
  float* out = (float*)d_out;

  const size_t xm_bytes    = (size_t)NSLICE64 * SLICE_US * 2;      // 2,621,440
  const size_t partz_bytes = (size_t)KSPLIT * N_NODES * 32 * 4;    // 8,388,608
  if (ws_size < MASK_WS + xm_bytes + partz_bytes) return;  // need ~11 MB

  unsigned char* mk = (unsigned char*)d_ws;
  unsigned short* XmG = (unsigned short*)((char*)d_ws + MASK_WS);
  float* partZ = (float*)((char*)d_ws + MASK_WS + xm_bytes);

  prep_kernel<<<dim3(NSLICE64), 256, 0, stream>>>(X, keep_raw, mk, XmG);
  gemm_kernel<<<dim3(N_NODES / 128, KSPLIT), 512, 0, stream>>>(A, XmG, mk, partZ);
  epi_kernel<<<dim3(N_NODES / 64), 64, 0, stream>>>(partZ, W, b, out);
}

// Round 12
// 100.957 us; speedup vs baseline: 1.1951x; 1.1951x over previous
//
#include <hip/hip_runtime.h>

// DropGCN: out = relu( mean_r( diag(k_r) A diag(k_r) X ) @ W^T + b )
//  == Y[8192,160] = A @ Xm   (Xm[:, r*32+d] = k_r .* X[:,d], bf16)
//  then per-row masked mean over the 5 replica slices, @W^T, +b, relu.
//
// Round 12: r8 champion skeleton (256-row blocks, 8 waves x 2 m-tiles,
// KSPLIT=8, reg-staged swizzled LDS, A in registers) with the block-wide
// barrier hoisted from EVERY K-step to every 4th step: LDS = 2 x 4-slice
// mega-buffers (80 KB), 8 barriers/block instead of 32. Within a mega the
// 4 K-steps run with no synchronization -> waves self-pace like the 7 TB/s
// fill/copy kernels (every synced variant r4-r11 stuck at ~3.2 TB/s).
// Staging: uniform 5 chunks/thread per mega, loaded a full mega ahead.

#define N_NODES   8192
#define NSLICES   256          // 8192/32 K-slices
#define NCOLS     160          // 5 replicas * 32 dims
#define SLICE_US  5120         // ushorts per K-slice image (160*32)
#define MASK_WS   65536        // ws bytes reserved for normalized mask
#define KSPLIT    8
#define STEPS     32           // K-steps per block (1024 k)
#define MEGAS     8            // 4 steps per mega
#define MEGA_US   (4 * SLICE_US)

typedef __attribute__((ext_vector_type(4))) float f32x4;
typedef __attribute__((ext_vector_type(8))) short bf16x8;

__device__ __forceinline__ unsigned short f2bf(float f) {
  // round-to-nearest-even f32 -> bf16 bits
  unsigned int u = __builtin_bit_cast(unsigned int, f);
  return (unsigned short)((u + 0x7FFFu + ((u >> 16) & 1u)) >> 16);
}

__device__ __forceinline__ unsigned pack_bf(float lo, float hi) {
  // two f32 -> packed bf16 pair (round-to-nearest ties-up; verified r3-r11)
  unsigned u0 = __builtin_bit_cast(unsigned, lo) + 0x8000u;
  unsigned u1 = __builtin_bit_cast(unsigned, hi) + 0x8000u;
  return (u1 & 0xFFFF0000u) | (u0 >> 16);
}

// ---------------------------------------------------------------------------
// prep (r8-verified, unchanged): block s handles K-slice s, all coalesced.
// LINEAR XmG layout: chunk c (16 B) = (n = c>>2, kg = c&3), kk = kg*8+e.
// ---------------------------------------------------------------------------
__global__ __launch_bounds__(256) void prep_kernel(
    const float* __restrict__ X, const void* __restrict__ raw,
    unsigned char* __restrict__ mk, unsigned short* __restrict__ XmG) {
  __shared__ float xt[32 * 33];   // [kk][d], pad 33
  __shared__ float mf[160];       // [r][kk] 0/1
  __shared__ int mode32s;
  const int tid = threadIdx.x;
  const int s = blockIdx.x;

  if (tid == 0) {
    const unsigned* wrd = (const unsigned*)raw;
    int ok = 1;
    for (int i = 0; i < 64; ++i) {
      unsigned v = wrd[i];
      if (!(v <= 1u || v == 0x3F800000u)) { ok = 0; break; }
    }
    mode32s = ok;
  }
  f32x4 xv = *(const f32x4*)(X + (size_t)s * 1024 + tid * 4);
  __syncthreads();
  const int mode32 = mode32s;
#pragma unroll
  for (int q = 0; q < 4; ++q) {
    int e = tid * 4 + q;                 // e = jj*32 + d
    xt[(e >> 5) * 33 + (e & 31)] = xv[q];
  }
  if (tid < 160) {
    int r = tid >> 5, jj = tid & 31;
    int gi = r * N_NODES + s * 32 + jj;
    unsigned char kv = mode32 ? (unsigned char)(((const unsigned*)raw)[gi] != 0u)
                              : (unsigned char)(((const unsigned char*)raw)[gi] != 0);
    mk[gi] = kv;
    mf[tid] = kv ? 1.0f : 0.0f;
  }
  __syncthreads();

  unsigned short* outp = XmG + (size_t)s * SLICE_US;
  for (int c = tid; c < 640; c += 256) {
    int n = c >> 2, kg = c & 3;          // LINEAR layout
    int r = n >> 5, d = n & 31;
    union { bf16x8 v; unsigned short us[8]; } o;
#pragma unroll
    for (int e = 0; e < 8; ++e) {
      int kk = kg * 8 + e;
      o.us[e] = f2bf(mf[r * 32 + kk] * xt[kk * 33 + d]);
    }
    *(bf16x8*)(outp + c * 8) = o.v;
  }
}

// ---------------------------------------------------------------------------
// gemm: block = 8 waves x 32 rows = 256 rows, all 160 cols, K-range 1024.
// grid (32, 8) = 256 blocks. LDS = 2 mega-buffers x 4 slices (80 KB).
// Per mega (4 K-steps): [ds_write mega+1 from regs][issue loads mega+2]
// [4 barrier-FREE K-steps: roll A regs, pack, 10 ds_read + 20 MFMA]
// [__syncthreads]. Swizzle (r8-verified): slice ushort (n*32+kg*8+e) at LDS
// n*32 + ((kg ^ ((n>>1)&3))*8) + e; XmG linear; swizzle applied at ds_write.
// Verified D map: acc[nt][jj] = Y[base_m + n0][nt*16 + kg*4 + jj].
// Fused replica mask-mean epilogue -> partZ[sy][m][d] f32.
// ---------------------------------------------------------------------------
__global__ __launch_bounds__(512, 2) void gemm_kernel(
    const float* __restrict__ A, const unsigned short* __restrict__ XmG,
    const unsigned char* __restrict__ mk, float* __restrict__ partZ) {
  __shared__ __align__(16) unsigned short xm[2][MEGA_US];   // 80 KB

  const int tid  = threadIdx.x;
  const int lane = tid & 63;
  const int w    = tid >> 6;        // wave 0..7
  const int n0   = lane & 15;
  const int kg   = lane >> 4;       // k-group 0..3 (8 elems each)
  const int sy   = blockIdx.y;      // k-split 0..7
  const int s_base = sy * STEPS;
  const int base_m = blockIdx.x * 256 + w * 32;   // wave owns 32 rows

  // A rows for the wave's two 16-row tiles
  const float* aptr0 =
      A + (size_t)(base_m + n0) * N_NODES + s_base * 32 + kg * 8;
  const float* aptr1 = aptr0 + (size_t)16 * N_NODES;

  // Xm staging: 2560 chunks per mega over 512 threads = 5 each (uniform).
  // chunk i = tid + j*512: slice s_in = i/640, c = i - s_in*640,
  // n = c>>2, kgs = c&3 -> swizzled LDS offset (within mega buffer).
  const unsigned short* gsrc = XmG + (size_t)s_base * SLICE_US;
  int ldsoff[5];
#pragma unroll
  for (int j = 0; j < 5; ++j) {
    int i = tid + j * 512;
    int s_in = i / 640;
    int c = i - s_in * 640;
    int n = c >> 2, kgs = c & 3;
    ldsoff[j] = s_in * SLICE_US + n * 32 + ((kgs ^ ((n >> 1) & 3)) << 3);
  }
  bf16x8 sg0, sg1, sg2, sg3, sg4;   // staged mega (named, rule #20)

#define LOAD_MEGA(m)                                                           \
  {                                                                            \
    const unsigned short* p_ = gsrc + (size_t)(m)*MEGA_US;                     \
    sg0 = *(const bf16x8*)(p_ + (tid)*8);                                      \
    sg1 = *(const bf16x8*)(p_ + (tid + 512) * 8);                              \
    sg2 = *(const bf16x8*)(p_ + (tid + 1024) * 8);                             \
    sg3 = *(const bf16x8*)(p_ + (tid + 1536) * 8);                             \
    sg4 = *(const bf16x8*)(p_ + (tid + 2048) * 8);                             \
  }

#define WRITE_MEGA(buf)                                                        \
  {                                                                            \
    unsigned short* d_ = &xm[buf][0];                                          \
    *(bf16x8*)(d_ + ldsoff[0]) = sg0;                                          \
    *(bf16x8*)(d_ + ldsoff[1]) = sg1;                                          \
    *(bf16x8*)(d_ + ldsoff[2]) = sg2;                                          \
    *(bf16x8*)(d_ + ldsoff[3]) = sg3;                                          \
    *(bf16x8*)(d_ + ldsoff[4]) = sg4;                                          \
  }

  // fragment read base (swizzled slot depends only on n0,kg)
  const int frag0 = n0 * 32 + ((kg ^ ((n0 >> 1) & 3)) << 3);

  f32x4 acc0[10], acc1[10];
#pragma unroll
  for (int i = 0; i < 10; ++i) {
    acc0[i] = (f32x4){0.f, 0.f, 0.f, 0.f};
    acc1[i] = (f32x4){0.f, 0.f, 0.f, 0.f};
  }

  // prologue: mega0 -> LDS buf0; mega1 -> regs; A step-0 regs
  LOAD_MEGA(0);
  WRITE_MEGA(0);
  LOAD_MEGA(1);
  f32x4 a0  = __builtin_nontemporal_load((const f32x4*)aptr0);
  f32x4 a0b = __builtin_nontemporal_load((const f32x4*)(aptr0 + 4));
  f32x4 a1  = __builtin_nontemporal_load((const f32x4*)aptr1);
  f32x4 a1b = __builtin_nontemporal_load((const f32x4*)(aptr1 + 4));
  __syncthreads();

  int cur = 0;
  for (int mega = 0; mega < MEGAS; ++mega) {
    if (mega + 1 < MEGAS) { WRITE_MEGA(cur ^ 1); }   // regs hold mega+1
    if (mega + 2 < MEGAS) { LOAD_MEGA(mega + 2); }   // deep prefetch

#pragma unroll
    for (int t = 0; t < 4; ++t) {                    // barrier-free K-steps
      const int step = mega * 4 + t;
      const int nxt = (step + 1 < STEPS) ? (step + 1) : step;
      f32x4 na0  = __builtin_nontemporal_load((const f32x4*)(aptr0 + (size_t)nxt * 32));
      f32x4 na0b = __builtin_nontemporal_load((const f32x4*)(aptr0 + (size_t)nxt * 32 + 4));
      f32x4 na1  = __builtin_nontemporal_load((const f32x4*)(aptr1 + (size_t)nxt * 32));
      f32x4 na1b = __builtin_nontemporal_load((const f32x4*)(aptr1 + (size_t)nxt * 32 + 4));

      union { bf16x8 v; unsigned u[4]; } b0, b1;
      b0.u[0] = pack_bf(a0[0], a0[1]);   b0.u[1] = pack_bf(a0[2], a0[3]);
      b0.u[2] = pack_bf(a0b[0], a0b[1]); b0.u[3] = pack_bf(a0b[2], a0b[3]);
      b1.u[0] = pack_bf(a1[0], a1[1]);   b1.u[1] = pack_bf(a1[2], a1[3]);
      b1.u[2] = pack_bf(a1b[0], a1b[1]); b1.u[3] = pack_bf(a1b[2], a1b[3]);

      const unsigned short* fb = &xm[cur][t * SLICE_US] + frag0;
#pragma unroll
      for (int nt = 0; nt < 10; ++nt) {
        bf16x8 af = *(const bf16x8*)(fb + nt * 512);
        acc0[nt] = __builtin_amdgcn_mfma_f32_16x16x32_bf16(af, b0.v, acc0[nt], 0, 0, 0);
        acc1[nt] = __builtin_amdgcn_mfma_f32_16x16x32_bf16(af, b1.v, acc1[nt], 0, 0, 0);
      }
      a0 = na0; a0b = na0b; a1 = na1; a1b = na1b;
    }
    __syncthreads();   // reads of buf[cur] done; buf[cur^1] writes visible
    cur ^= 1;
  }

  // fused replica mask-mean epilogue (r8-verified map):
  // acc[2t][jj]  = Y[m][32t + kg*4+jj]       (d = kg*4+jj,    r = t)
  // acc[2t+1][jj]= Y[m][32t + 16 + kg*4+jj]  (d = kg*4+jj+16, r = t)
  const int m0g = base_m + n0;
  const int m1g = m0g + 16;
  float w0[5], w1[5];
#pragma unroll
  for (int t = 0; t < 5; ++t) {
    w0[t] = mk[t * N_NODES + m0g] ? 0.2f : 0.0f;
    w1[t] = mk[t * N_NODES + m1g] ? 0.2f : 0.0f;
  }
  f32x4 zA0 = (f32x4){0.f, 0.f, 0.f, 0.f}, zB0 = zA0, zA1 = zA0, zB1 = zA0;
#pragma unroll
  for (int t = 0; t < 5; ++t) {
    zA0 += w0[t] * acc0[2 * t];
    zB0 += w0[t] * acc0[2 * t + 1];
    zA1 += w1[t] * acc1[2 * t];
    zB1 += w1[t] * acc1[2 * t + 1];
  }
  float* p0 = partZ + ((size_t)sy * N_NODES + m0g) * 32 + kg * 4;
  *(f32x4*)(p0)      = zA0;
  *(f32x4*)(p0 + 16) = zB0;
  float* p1 = partZ + ((size_t)sy * N_NODES + m1g) * 32 + kg * 4;
  *(f32x4*)(p1)      = zA1;
  *(f32x4*)(p1 + 16) = zB1;
}

// ---------------------------------------------------------------------------
// epi: z[m][d] = sum_s partZ[s][m][d];  out[m][o] = relu(b[o] + z . W[o])
// ---------------------------------------------------------------------------
__global__ __launch_bounds__(64) void epi_kernel(
    const float* __restrict__ partZ, const float* __restrict__ W,
    const float* __restrict__ bias, float* __restrict__ out) {
  __shared__ float sW[1024];
  __shared__ float sb[32];
  const int tid = threadIdx.x;
  for (int i = tid; i < 1024; i += 64) sW[i] = W[i];
  if (tid < 32) sb[tid] = bias[tid];
  __syncthreads();

  const int m = blockIdx.x * 64 + tid;
  float zz[32];
#pragma unroll
  for (int i = 0; i < 32; ++i) zz[i] = 0.f;
  const float* p = partZ + (size_t)m * 32;
  for (int s = 0; s < KSPLIT; ++s) {
    const float* ps = p + (size_t)s * N_NODES * 32;
#pragma unroll
    for (int i = 0; i < 8; ++i) {
      f32x4 v = *(const f32x4*)(ps + i * 4);
      zz[4 * i + 0] += v[0]; zz[4 * i + 1] += v[1];
      zz[4 * i + 2] += v[2]; zz[4 * i + 3] += v[3];
    }
  }
#pragma unroll
  for (int o = 0; o < 32; o += 4) {
    f32x4 r;
#pragma unroll
    for (int q = 0; q < 4; ++q) {
      float a = sb[o + q];
#pragma unroll
      for (int d = 0; d < 32; ++d) a = fmaf(zz[d], sW[(o + q) * 32 + d], a);
      r[q] = fmaxf(a, 0.f);
    }
    *(f32x4*)(out + (size_t)m * 32 + o) = r;
  }
}

extern "C" void kernel_launch(void* const* d_in, const int* in_sizes, int n_in,
                              void* d_out, int out_size, void* d_ws, size_t ws_size,
                              hipStream_t stream) {
  const float* A = (const float*)d_in[0];
  const float* X = (const float*)d_in[1];
  const float* W = (const float*)d_in[2];
  const float* b = (const float*)d_in[3];
  const void*  keep_raw = (const void*)d_in[4];
  float* out = (float*)d_out;

  const size_t xm_bytes    = (size_t)NSLICES * SLICE_US * 2;       // 2,621,440
  const size_t partz_bytes = (size_t)KSPLIT * N_NODES * 32 * 4;    // 8,388,608
  if (ws_size < MASK_WS + xm_bytes + partz_bytes) return;  // need ~11 MB

  unsigned char* mk = (unsigned char*)d_ws;
  unsigned short* XmG = (unsigned short*)((char*)d_ws + MASK_WS);
  float* partZ = (float*)((char*)d_ws + MASK_WS + xm_bytes);

  prep_kernel<<<dim3(NSLICES), 256, 0, stream>>>(X, keep_raw, mk, XmG);
  gemm_kernel<<<dim3(N_NODES / 256, KSPLIT), 512, 0, stream>>>(A, XmG, mk, partZ);
  epi_kernel<<<dim3(N_NODES / 64), 64, 0, stream>>>(partZ, W, b, out);
}

// Round 13
// 68.357 us; speedup vs baseline: 1.7650x; 1.4769x over previous
//
#include <hip/hip_runtime.h>

// DropGCN: out = relu( mean_r( diag(k_r) A diag(k_r) X ) @ W^T + b )
//  == Y[8192,160] = A @ Xm   (Xm[:, r*32+d] = k_r .* X[:,d], bf16)
//  then per-row masked mean over the 5 replica slices, @W^T, +b, relu.
//
// Round 13: r8 champion (93.5 us) byte-for-byte EXCEPT the A-prefetch loads
// are plain f32x4 loads instead of __builtin_nontemporal_load. nt was
// constant across ALL r2-r12 variants (every one stuck at ~3.2 TB/s on the
// A-stream); the 6.3-7 TB/s references (fills, float4 copy) use plain
// accesses. Hypothesis: nt bypasses L2/MALL miss buffering that coalesces
// scattered 128 B requests into DRAM-friendly bursts. Single-variable A/B.

#define N_NODES   8192
#define NSLICES   256          // 8192/32 K-slices
#define NCOLS     160          // 5 replicas * 32 dims
#define SLICE_US  5120         // ushorts per K-slice image (160*32)
#define MASK_WS   65536        // ws bytes reserved for normalized mask
#define KSPLIT    8
#define STEPS     (NSLICES / KSPLIT)   // 32 K-steps per block

typedef __attribute__((ext_vector_type(4))) float f32x4;
typedef __attribute__((ext_vector_type(8))) short bf16x8;

__device__ __forceinline__ unsigned short f2bf(float f) {
  // round-to-nearest-even f32 -> bf16 bits
  unsigned int u = __builtin_bit_cast(unsigned int, f);
  return (unsigned short)((u + 0x7FFFu + ((u >> 16) & 1u)) >> 16);
}

__device__ __forceinline__ unsigned pack_bf(float lo, float hi) {
  // two f32 -> packed bf16 pair (round-to-nearest ties-up; verified r3-r12)
  unsigned u0 = __builtin_bit_cast(unsigned, lo) + 0x8000u;
  unsigned u1 = __builtin_bit_cast(unsigned, hi) + 0x8000u;
  return (u1 & 0xFFFF0000u) | (u0 >> 16);
}

// ---------------------------------------------------------------------------
// prep (r8-verified, unchanged): block s handles K-slice s, all coalesced.
// LINEAR XmG layout: chunk c (16 B) = (n = c>>2, kg = c&3), kk = kg*8+e.
// ---------------------------------------------------------------------------
__global__ __launch_bounds__(256) void prep_kernel(
    const float* __restrict__ X, const void* __restrict__ raw,
    unsigned char* __restrict__ mk, unsigned short* __restrict__ XmG) {
  __shared__ float xt[32 * 33];   // [kk][d], pad 33
  __shared__ float mf[160];       // [r][kk] 0/1
  __shared__ int mode32s;
  const int tid = threadIdx.x;
  const int s = blockIdx.x;

  if (tid == 0) {
    const unsigned* wrd = (const unsigned*)raw;
    int ok = 1;
    for (int i = 0; i < 64; ++i) {
      unsigned v = wrd[i];
      if (!(v <= 1u || v == 0x3F800000u)) { ok = 0; break; }
    }
    mode32s = ok;
  }
  f32x4 xv = *(const f32x4*)(X + (size_t)s * 1024 + tid * 4);
  __syncthreads();
  const int mode32 = mode32s;
#pragma unroll
  for (int q = 0; q < 4; ++q) {
    int e = tid * 4 + q;                 // e = jj*32 + d
    xt[(e >> 5) * 33 + (e & 31)] = xv[q];
  }
  if (tid < 160) {
    int r = tid >> 5, jj = tid & 31;
    int gi = r * N_NODES + s * 32 + jj;
    unsigned char kv = mode32 ? (unsigned char)(((const unsigned*)raw)[gi] != 0u)
                              : (unsigned char)(((const unsigned char*)raw)[gi] != 0);
    mk[gi] = kv;
    mf[tid] = kv ? 1.0f : 0.0f;
  }
  __syncthreads();

  unsigned short* outp = XmG + (size_t)s * SLICE_US;
  for (int c = tid; c < 640; c += 256) {
    int n = c >> 2, kg = c & 3;          // LINEAR layout
    int r = n >> 5, d = n & 31;
    union { bf16x8 v; unsigned short us[8]; } o;
#pragma unroll
    for (int e = 0; e < 8; ++e) {
      int kk = kg * 8 + e;
      o.us[e] = f2bf(mf[r * 32 + kk] * xt[kk * 33 + d]);
    }
    *(bf16x8*)(outp + c * 8) = o.v;
  }
}

// ---------------------------------------------------------------------------
// gemm (r8 structure, verbatim except plain A loads): block = 8 waves x 32
// rows = 256 rows, all 160 cols, K-range 1024. LDS double-buffer of one
// 10 KB K-slice, 1 barrier/step, reg-staged with XOR swizzle: slice ushort
// (n*32+kg*8+e) at LDS ushort n*32 + ((kg ^ ((n>>1)&3))*8) + e.
// Verified D map: acc[nt][jj] = Y[base_m + n0][nt*16 + kg*4 + jj].
// Fused replica mask-mean epilogue -> partZ[sy][m][d] f32.
// ---------------------------------------------------------------------------
__global__ __launch_bounds__(512, 2) void gemm_kernel(
    const float* __restrict__ A, const unsigned short* __restrict__ XmG,
    const unsigned char* __restrict__ mk, float* __restrict__ partZ) {
  __shared__ __align__(16) unsigned short xm[2][SLICE_US];   // 20 KB

  const int tid  = threadIdx.x;
  const int lane = tid & 63;
  const int w    = tid >> 6;        // wave 0..7
  const int n0   = lane & 15;
  const int kg   = lane >> 4;       // k-group 0..3 (8 elems each)
  const int sy   = blockIdx.y;      // k-split 0..7
  const int s_base = sy * STEPS;
  const int base_m = blockIdx.x * 256 + w * 32;   // wave owns 32 rows

  // A rows for the wave's two 16-row tiles
  const float* aptr0 =
      A + (size_t)(base_m + n0) * N_NODES + s_base * 32 + kg * 8;
  const float* aptr1 = aptr0 + (size_t)16 * N_NODES;

  // staging: thread stages chunk c0=tid (and c1=tid+512 if tid<128);
  // chunk c = 16 B at slice ushort c*8 -> n = c>>2, kgs = c&3
  const unsigned short* xsrc = XmG + (size_t)s_base * SLICE_US;
  const int c0 = tid, n_c0 = c0 >> 2;
  const int off0 = n_c0 * 32 + (((c0 & 3) ^ ((n_c0 >> 1) & 3)) << 3);
  const int c1 = tid + 512, n_c1 = c1 >> 2;
  const int off1 = n_c1 * 32 + (((c1 & 3) ^ ((n_c1 >> 1) & 3)) << 3);
  const bool has2 = (tid < 128);

  // fragment read base (swizzled slot depends only on n0,kg)
  const unsigned short* frag0 =
      &xm[0][0] + n0 * 32 + ((kg ^ ((n0 >> 1) & 3)) << 3);

  f32x4 acc0[10], acc1[10];
#pragma unroll
  for (int i = 0; i < 10; ++i) {
    acc0[i] = (f32x4){0.f, 0.f, 0.f, 0.f};
    acc1[i] = (f32x4){0.f, 0.f, 0.f, 0.f};
  }

  // prologue: slice 0 -> regs -> LDS buf0; slice 1 -> regs; A step-0 regs
  bf16x8 sa = *(const bf16x8*)(xsrc + c0 * 8);
  bf16x8 sb2 = sa;
  if (has2) sb2 = *(const bf16x8*)(xsrc + c1 * 8);
  f32x4 a0  = *(const f32x4*)aptr0;
  f32x4 a0b = *(const f32x4*)(aptr0 + 4);
  f32x4 a1  = *(const f32x4*)aptr1;
  f32x4 a1b = *(const f32x4*)(aptr1 + 4);
  *(bf16x8*)(&xm[0][off0]) = sa;
  if (has2) *(bf16x8*)(&xm[0][off1]) = sb2;
  sa = *(const bf16x8*)(xsrc + SLICE_US + c0 * 8);
  if (has2) sb2 = *(const bf16x8*)(xsrc + SLICE_US + c1 * 8);
  __syncthreads();

  int cur = 0;
  for (int step = 0; step < STEPS; ++step) {
    // stage slice step+1 into the other buffer (its prior readers finished
    // before the barrier that ended step-1)
    if (step + 1 < STEPS) {
      unsigned short* dst = &xm[cur ^ 1][0];
      *(bf16x8*)(dst + off0) = sa;
      if (has2) *(bf16x8*)(dst + off1) = sb2;
    }
    // issue global load of slice step+2 (lands during compute + barrier)
    if (step + 2 < STEPS) {
      const unsigned short* s2 = xsrc + (size_t)(step + 2) * SLICE_US;
      sa = *(const bf16x8*)(s2 + c0 * 8);
      if (has2) sb2 = *(const bf16x8*)(s2 + c1 * 8);
    }
    // prefetch next step's A registers (PLAIN loads this round — the A/B)
    const int nxt = (step + 1 < STEPS) ? (step + 1) : step;
    f32x4 na0  = *(const f32x4*)(aptr0 + (size_t)nxt * 32);
    f32x4 na0b = *(const f32x4*)(aptr0 + (size_t)nxt * 32 + 4);
    f32x4 na1  = *(const f32x4*)(aptr1 + (size_t)nxt * 32);
    f32x4 na1b = *(const f32x4*)(aptr1 + (size_t)nxt * 32 + 4);

    // pack B fragments (same lane->k map as A-op; permutation cancels)
    union { bf16x8 v; unsigned u[4]; } b0, b1;
    b0.u[0] = pack_bf(a0[0], a0[1]);   b0.u[1] = pack_bf(a0[2], a0[3]);
    b0.u[2] = pack_bf(a0b[0], a0b[1]); b0.u[3] = pack_bf(a0b[2], a0b[3]);
    b1.u[0] = pack_bf(a1[0], a1[1]);   b1.u[1] = pack_bf(a1[2], a1[3]);
    b1.u[2] = pack_bf(a1b[0], a1b[1]); b1.u[3] = pack_bf(a1b[2], a1b[3]);

    const unsigned short* fb = frag0 + cur * SLICE_US;
#pragma unroll
    for (int nt = 0; nt < 10; ++nt) {
      bf16x8 af = *(const bf16x8*)(fb + nt * 512);
      acc0[nt] = __builtin_amdgcn_mfma_f32_16x16x32_bf16(af, b0.v, acc0[nt], 0, 0, 0);
      acc1[nt] = __builtin_amdgcn_mfma_f32_16x16x32_bf16(af, b1.v, acc1[nt], 0, 0, 0);
    }
    __syncthreads();   // reads of buf[cur] done; buf[cur^1] writes visible
    cur ^= 1;
    a0 = na0; a0b = na0b; a1 = na1; a1b = na1b;
  }

  // fused replica mask-mean epilogue:
  // acc[2t][jj]  = Y[m][32t + kg*4+jj]       (d = kg*4+jj,    r = t)
  // acc[2t+1][jj]= Y[m][32t + 16 + kg*4+jj]  (d = kg*4+jj+16, r = t)
  const int m0g = base_m + n0;
  const int m1g = m0g + 16;
  float w0[5], w1[5];
#pragma unroll
  for (int t = 0; t < 5; ++t) {
    w0[t] = mk[t * N_NODES + m0g] ? 0.2f : 0.0f;
    w1[t] = mk[t * N_NODES + m1g] ? 0.2f : 0.0f;
  }
  f32x4 zA0 = (f32x4){0.f, 0.f, 0.f, 0.f}, zB0 = zA0, zA1 = zA0, zB1 = zA0;
#pragma unroll
  for (int t = 0; t < 5; ++t) {
    zA0 += w0[t] * acc0[2 * t];
    zB0 += w0[t] * acc0[2 * t + 1];
    zA1 += w1[t] * acc1[2 * t];
    zB1 += w1[t] * acc1[2 * t + 1];
  }
  float* p0 = partZ + ((size_t)sy * N_NODES + m0g) * 32 + kg * 4;
  *(f32x4*)(p0)      = zA0;
  *(f32x4*)(p0 + 16) = zB0;
  float* p1 = partZ + ((size_t)sy * N_NODES + m1g) * 32 + kg * 4;
  *(f32x4*)(p1)      = zA1;
  *(f32x4*)(p1 + 16) = zB1;
}

// ---------------------------------------------------------------------------
// epi: z[m][d] = sum_s partZ[s][m][d];  out[m][o] = relu(b[o] + z . W[o])
// ---------------------------------------------------------------------------
__global__ __launch_bounds__(64) void epi_kernel(
    const float* __restrict__ partZ, const float* __restrict__ W,
    const float* __restrict__ bias, float* __restrict__ out) {
  __shared__ float sW[1024];
  __shared__ float sb[32];
  const int tid = threadIdx.x;
  for (int i = tid; i < 1024; i += 64) sW[i] = W[i];
  if (tid < 32) sb[tid] = bias[tid];
  __syncthreads();

  const int m = blockIdx.x * 64 + tid;
  float zz[32];
#pragma unroll
  for (int i = 0; i < 32; ++i) zz[i] = 0.f;
  const float* p = partZ + (size_t)m * 32;
  for (int s = 0; s < KSPLIT; ++s) {
    const float* ps = p + (size_t)s * N_NODES * 32;
#pragma unroll
    for (int i = 0; i < 8; ++i) {
      f32x4 v = *(const f32x4*)(ps + i * 4);
      zz[4 * i + 0] += v[0]; zz[4 * i + 1] += v[1];
      zz[4 * i + 2] += v[2]; zz[4 * i + 3] += v[3];
    }
  }
#pragma unroll
  for (int o = 0; o < 32; o += 4) {
    f32x4 r;
#pragma unroll
    for (int q = 0; q < 4; ++q) {
      float a = sb[o + q];
#pragma unroll
      for (int d = 0; d < 32; ++d) a = fmaf(zz[d], sW[(o + q) * 32 + d], a);
      r[q] = fmaxf(a, 0.f);
    }
    *(f32x4*)(out + (size_t)m * 32 + o) = r;
  }
}

extern "C" void kernel_launch(void* const* d_in, const int* in_sizes, int n_in,
                              void* d_out, int out_size, void* d_ws, size_t ws_size,
                              hipStream_t stream) {
  const float* A = (const float*)d_in[0];
  const float* X = (const float*)d_in[1];
  const float* W = (const float*)d_in[2];
  const float* b = (const float*)d_in[3];
  const void*  keep_raw = (const void*)d_in[4];
  float* out = (float*)d_out;

  const size_t xm_bytes    = (size_t)NSLICES * SLICE_US * 2;       // 2,621,440
  const size_t partz_bytes = (size_t)KSPLIT * N_NODES * 32 * 4;    // 8,388,608
  if (ws_size < MASK_WS + xm_bytes + partz_bytes) return;  // need ~11 MB

  unsigned char* mk = (unsigned char*)d_ws;
  unsigned short* XmG = (unsigned short*)((char*)d_ws + MASK_WS);
  float* partZ = (float*)((char*)d_ws + MASK_WS + xm_bytes);

  prep_kernel<<<dim3(NSLICES), 256, 0, stream>>>(X, keep_raw, mk, XmG);
  gemm_kernel<<<dim3(N_NODES / 256, KSPLIT), 512, 0, stream>>>(A, XmG, mk, partZ);
  epi_kernel<<<dim3(N_NODES / 64), 64, 0, stream>>>(partZ, W, b, out);
}